// Round 3
// baseline (190.934 us; speedup 1.0000x reference)
//
#include <hip/hip_runtime.h>
#include <hip/hip_bf16.h>

typedef __attribute__((ext_vector_type(8))) short short8;
typedef __attribute__((ext_vector_type(4))) float floatx4;

#define MARGIN 0.3f
static constexpr int N = 8192;   // b*n points
static constexpr int C = 256;    // feature dim

// async 16B global->LDS (dest = wave-uniform base + lane*16)
__device__ __forceinline__ void async16(const void* g, void* l) {
    __builtin_amdgcn_global_load_lds(
        (const __attribute__((address_space(1))) unsigned int*)g,
        (__attribute__((address_space(3))) unsigned int*)l, 16, 0, 0);
}

// ---------------- kernel 0: fp32->bf16 convert + row norms + init --------------
__global__ void k_prep_sq(const float* __restrict__ feat, __hip_bfloat16* __restrict__ fb,
                          float* __restrict__ sq, unsigned* __restrict__ posmax,
                          unsigned* __restrict__ negmin, float* __restrict__ scalars) {
    int row = blockIdx.x * 4 + (threadIdx.x >> 6);
    int lane = threadIdx.x & 63;
    float4 v = ((const float4*)feat)[row * 64 + lane];
    union { __hip_bfloat16 h[4]; ushort4 u; } cv;
    cv.h[0] = __float2bfloat16(v.x); cv.h[1] = __float2bfloat16(v.y);
    cv.h[2] = __float2bfloat16(v.z); cv.h[3] = __float2bfloat16(v.w);
    ((ushort4*)fb)[row * 64 + lane] = cv.u;
    float s = v.x * v.x + v.y * v.y + v.z * v.z + v.w * v.w;
#pragma unroll
    for (int off = 32; off; off >>= 1) s += __shfl_xor(s, off);
    if (lane == 0) {
        sq[row] = s;
        posmax[row] = 0u;
        negmin[row] = 0x7f800000u;   // +inf
    }
    if (blockIdx.x == 0 && threadIdx.x < 8) scalars[threadIdx.x] = 0.f;
}

// ---------------- kernel 1: symmetric pairwise mining via bf16 MFMA ------------
// d2(i,j) == d2(j,i): compute only tiles with jb >= ib. Off-diagonal tiles also
// emit mirrored updates (col-min for negmin, diag element for posmax) from the
// same accumulators. Grid: 64 i-tiles x 16 half-chunks (512 cols); blocks fully
// below the diagonal exit immediately. Labels have period 128 => same-label
// pairs inside any 128-aligned tile are exactly the tile diagonal.
__global__ __launch_bounds__(256, 2)
void k_trip(const __hip_bfloat16* __restrict__ fb, const float* __restrict__ sq,
            unsigned* __restrict__ posmax, unsigned* __restrict__ negmin) {
    __shared__ uint4 Bs[4096];   // 128 cols x 32 granules (16B each) = 64 KB

    const int it = blockIdx.x >> 4;
    const int h4 = blockIdx.x & 15;
    if ((h4 << 2) + 3 < it) return;           // whole chunk below diagonal

    const int t = threadIdx.x;
    const int ib = it * 128;                  // i-tile base row
    const int jc = h4 * 512;                  // j half-chunk base
    const int w = t >> 6, lane = t & 63;
    const int wi = w >> 1, wj = w & 1;
    const int quad = lane >> 4, l15 = lane & 15;

    // ---- A fragments in registers: rows wi*64 + ti*16 + l15, all K=256 ----
    short8 a[4][8];
#pragma unroll
    for (int ti = 0; ti < 4; ++ti) {
        const __hip_bfloat16* ap = fb + (size_t)(ib + wi * 64 + ti * 16 + l15) * C + quad * 8;
#pragma unroll
        for (int k = 0; k < 8; ++k)
            a[ti][k] = *(const short8*)(ap + k * 32);
    }

    float si[16];                 // ||x_i||^2 for this lane's 16 acc rows
#pragma unroll
    for (int q = 0; q < 16; ++q)
        si[q] = sq[ib + wi * 64 + (q >> 2) * 16 + quad * 4 + (q & 3)];

    float nm[16];                 // row-side running min of (sj - 2*dot)
    float pm[4];                  // row-side running max of diag (sj - 2*dot)
#pragma unroll
    for (int q = 0; q < 16; ++q) nm[q] = INFINITY;
#pragma unroll
    for (int q = 0; q < 4; ++q) pm[q] = -INFINITY;

#pragma unroll 1
    for (int jt = 0; jt < 4; ++jt) {
        const int jb = jc + jt * 128;
        if (jb < ib) continue;                 // block-uniform skip
        const bool mirror = (jb > ib);

        __syncthreads();                       // prior tile's LDS reads done
        // stage B tile (128 cols x K=256 bf16 = 64 KB), XOR-swizzled at source:
        // LDS slot s holds granule (s&31) ^ (row&7) of row s>>5.
#pragma unroll
        for (int st = 0; st < 16; ++st) {
            int s = st * 256 + t;
            int srow = s >> 5, sg = s & 31;
            int g = sg ^ (srow & 7);
            async16(fb + (size_t)(jb + srow) * C + g * 8, &Bs[st * 256 + (t & ~63)]);
        }
        __syncthreads();                       // staging complete

#pragma unroll
        for (int tjh = 0; tjh < 2; ++tjh) {    // two half-j passes (acc = 32 regs)
            floatx4 acc[4][2];
#pragma unroll
            for (int ti = 0; ti < 4; ++ti)
#pragma unroll
                for (int tjj = 0; tjj < 2; ++tjj)
                    acc[ti][tjj] = (floatx4){0.f, 0.f, 0.f, 0.f};

#pragma unroll
            for (int k = 0; k < 8; ++k) {
                short8 b[2];
#pragma unroll
                for (int tjj = 0; tjj < 2; ++tjj) {
                    int col = wj * 64 + (tjh * 2 + tjj) * 16 + l15;
                    int g = k * 4 + quad;
                    b[tjj] = *(const short8*)&Bs[col * 32 + (g ^ (col & 7))];
                }
#pragma unroll
                for (int ti = 0; ti < 4; ++ti)
#pragma unroll
                    for (int tjj = 0; tjj < 2; ++tjj)
                        acc[ti][tjj] = __builtin_amdgcn_mfma_f32_16x16x32_bf16(
                            a[ti][k], b[tjj], acc[ti][tjj], 0, 0, 0);
            }

            // mining epilogue: row-side on (sj - 2dot), mirrored col-side on (si - 2dot)
#pragma unroll
            for (int tjj = 0; tjj < 2; ++tjj) {
                int tj = tjh * 2 + tjj;
                int jjl = wj * 64 + tj * 16 + l15;      // local col 0..127
                float sj = sq[jb + jjl];
                float cm = INFINITY;                     // col-side min
#pragma unroll
                for (int ti = 0; ti < 4; ++ti) {
                    bool diag_tile = (wi == wj) && (ti == tj);
#pragma unroll
                    for (int r = 0; r < 4; ++r) {
                        float dot = acc[ti][tjj][r];
                        float vr = fmaf(-2.f, dot, sj);
                        bool isd = diag_tile && (l15 == quad * 4 + r);  // same label
                        nm[ti * 4 + r] = fminf(nm[ti * 4 + r], isd ? INFINITY : vr);
                        if (mirror) {
                            float vc = fmaf(-2.f, dot, si[ti * 4 + r]);
                            cm = fminf(cm, isd ? INFINITY : vc);
                            if (isd) {
                                pm[ti] = fmaxf(pm[ti], vr);
                                float d2p = fmaxf(vr + si[ti * 4 + r], 0.f);
                                atomicMax(&posmax[jb + jjl], __float_as_uint(d2p));
                            }
                        }
                    }
                }
                if (mirror) {
                    // reduce col-min across the 4 quads (lanes quad*16 + l15)
                    cm = fminf(cm, __shfl_xor(cm, 16));
                    cm = fminf(cm, __shfl_xor(cm, 32));
                    if (quad == 0) {
                        float d2 = fmaxf(cm + sj, 0.f);
                        atomicMin(&negmin[jb + jjl], __float_as_uint(d2));
                    }
                }
            }
        }
    }

    // ---- final: reduce nm across the 16 lanes of each quad; owner-lane pm ----
#pragma unroll
    for (int q = 0; q < 16; ++q) {
        float v = nm[q];
#pragma unroll
        for (int off = 1; off < 16; off <<= 1) v = fminf(v, __shfl_xor(v, off));
        if (l15 == 0) {
            int row = ib + wi * 64 + (q >> 2) * 16 + quad * 4 + (q & 3);
            float d2 = fmaxf(v + sq[row], 0.f);
            atomicMin(&negmin[row], __float_as_uint(d2));
        }
    }
    if (wi == wj && (l15 >> 2) == quad) {     // lanes owning tile-diag elements
#pragma unroll
        for (int ti = 0; ti < 4; ++ti) {
            int row = ib + wi * 64 + ti * 16 + l15;
            float d2 = fmaxf(pm[ti] + sq[row], 0.f);   // -inf+sq -> 0: harmless
            atomicMax(&posmax[row], __float_as_uint(d2));
        }
    }
}

// ---------------- kernel 2: mse + dr (tiny reductions) -------------------------
__global__ void k_small(const float* __restrict__ s0, const float* __restrict__ s1,
                        const float* __restrict__ s2, const float* __restrict__ g,
                        const float* __restrict__ e0, const float* __restrict__ e1,
                        const float* __restrict__ l0, const float* __restrict__ l1,
                        float* __restrict__ scalars) {
    const int E = 64 * 1024;
    int tid = blockIdx.x * 256 + threadIdx.x;
    int nth = gridDim.x * 256;
    float acc = 0.f;
    for (int i = tid; i < E; i += nth) acc += fabsf(e0[i] - l0[i]) * (1.f / E);
    for (int i = tid; i < E; i += nth) acc += fabsf(e1[i] - l1[i]) * (1.f / E);
    if (tid < 192) {
        int k = tid >> 6, i = tid & 63;
        const float* s = (k == 0) ? s0 : ((k == 1) ? s1 : s2);
        float d = s[i] - g[i];
        acc += d * d * (1.f / 192.f);
    }
#pragma unroll
    for (int off = 32; off; off >>= 1) acc += __shfl_xor(acc, off);
    __shared__ float red[4];
    int lane = threadIdx.x & 63, wv = threadIdx.x >> 6;
    if (lane == 0) red[wv] = acc;
    __syncthreads();
    if (threadIdx.x == 0)
        atomicAdd(&scalars[0], red[0] + red[1] + red[2] + red[3]);
}

// ---------------- kernel 3: final combine ---------------------------------------
__global__ void k_final(const unsigned* __restrict__ posmax, const unsigned* __restrict__ negmin,
                        const float* __restrict__ scalars, float* __restrict__ out) {
    float acc = 0.f;
    for (int i = threadIdx.x; i < N; i += 1024) {
        float hp = sqrtf(__uint_as_float(posmax[i]));
        float hn = sqrtf(__uint_as_float(negmin[i]));
        acc += fmaxf(hp - hn + MARGIN, 0.f);
    }
#pragma unroll
    for (int off = 32; off; off >>= 1) acc += __shfl_xor(acc, off);
    __shared__ float red[16];
    if ((threadIdx.x & 63) == 0) red[threadIdx.x >> 6] = acc;
    __syncthreads();
    if (threadIdx.x == 0) {
        float tsum = 0.f;
#pragma unroll
        for (int i = 0; i < 16; ++i) tsum += red[i];
        out[0] = scalars[0] + tsum * (1.f / N);
    }
}

extern "C" void kernel_launch(void* const* d_in, const int* in_sizes, int n_in,
                              void* d_out, int out_size, void* d_ws, size_t ws_size,
                              hipStream_t stream) {
    const float* feat = (const float*)d_in[0];
    const float* gt   = (const float*)d_in[1];
    const float* s0   = (const float*)d_in[2];
    const float* s1   = (const float*)d_in[3];
    const float* s2   = (const float*)d_in[4];
    const float* e0   = (const float*)d_in[5];
    const float* e1   = (const float*)d_in[6];
    const float* l0   = (const float*)d_in[7];
    const float* l1   = (const float*)d_in[8];
    float* out = (float*)d_out;

    char* ws = (char*)d_ws;
    __hip_bfloat16* fb = (__hip_bfloat16*)ws;                       // 4 MB
    float*    sq      = (float*)(ws + (size_t)N * C * 2);
    unsigned* posmax  = (unsigned*)(ws + (size_t)N * C * 2 + N * 4);
    unsigned* negmin  = (unsigned*)(ws + (size_t)N * C * 2 + N * 8);
    float*    scalars = (float*)(ws + (size_t)N * C * 2 + N * 12);

    k_prep_sq<<<N / 4, 256, 0, stream>>>(feat, fb, sq, posmax, negmin, scalars);
    k_trip<<<1024, 256, 0, stream>>>(fb, sq, posmax, negmin);
    k_small<<<64, 256, 0, stream>>>(s0, s1, s2, gt, e0, e1, l0, l1, scalars);
    k_final<<<1, 1024, 0, stream>>>(posmax, negmin, scalars, out);
}